// Round 13
// baseline (250.060 us; speedup 1.0000x reference)
//
#include <hip/hip_runtime.h>

// Paired CGCNN (separated) — R13.
// R13 vs R12 (k_convfused only): wave w owns cols [16w,16w+16)+[64+16w,...)
// so filt/core for feature f sit in the SAME lane (acc[0]/acc[1]) -> epilogue
// runs from registers; sZ spill + one barrier removed; partial sums go via a
// 3KB padded LDS array (deterministic 3-term sum). LDS 27KB -> ~11.7KB,
// launch_bounds(256,6). Identical arithmetic chain to R12.

constexpr int NATOM = 20000;
constexpr int MNBR  = 12;
constexpr int ORIG  = 92;
constexpr int NBRF  = 41;
constexpr int F     = 64;
constexpr int H     = 128;
constexpr int NCONV = 3;
constexpr int NCRYS = 400;

#define DEVFN __device__ __forceinline__

typedef __attribute__((ext_vector_type(8))) short short8;
typedef __attribute__((ext_vector_type(4))) float f32x4;

DEVFN float softplusf(float x) {
    return fmaxf(x, 0.f) + __logf(1.f + __expf(-fabsf(x)));
}
DEVFN float sigmoidf(float x) {
    return __builtin_amdgcn_rcpf(1.f + __expf(-x));
}
DEVFN unsigned short f2bf(float x) {
    union { float f; unsigned u; } v{x};
    unsigned r = v.u + 0x7FFF + ((v.u >> 16) & 1);
    return (unsigned short)(r >> 16);
}
DEVFN float bf2f(unsigned short h) {
    union { unsigned u; float f; } v;
    v.u = (unsigned)h << 16;
    return v.f;
}
DEVFN unsigned pk2(float a, float b) {
    return (unsigned)f2bf(a) | ((unsigned)f2bf(b) << 16);
}
DEVFN unsigned short f2h(float x) {
    _Float16 h = (_Float16)x;
    union { _Float16 h; unsigned short u; } v{h};
    return v.u;
}
DEVFN float h2f(unsigned short u) {
    union { unsigned short u; _Float16 h; } v{u};
    return (float)v.h;
}
DEVFN unsigned packlo(unsigned a, unsigned b) { return (a & 0xffffu) | (b << 16); }
DEVFN unsigned packhi(unsigned a, unsigned b) { return (a >> 16) | (b & 0xffff0000u); }

// ------- wcvt -------
__global__ __launch_bounds__(256) void k_wcvt(const float* __restrict__ convW_A,
                                              const float* __restrict__ convW_B,
                                              const float* __restrict__ embWA,
                                              const float* __restrict__ embWB,
                                              unsigned* __restrict__ w3t,
                                              unsigned* __restrict__ w12h,
                                              unsigned* __restrict__ w12l,
                                              unsigned* __restrict__ embh,
                                              unsigned* __restrict__ embl) {
    int e = blockIdx.x * 256 + threadIdx.x;
    if (e < 24576) {
        int mat = e >> 12;
        int rem = e & 4095;
        int col = rem >> 5, kp = rem & 31, k = kp * 2;
        int br = mat / 3, l = mat - br * 3;
        const float* src = (br ? convW_B : convW_A) + (size_t)l * (2 * F + NBRF) * H + 128 * H;
        float v0 = (k < NBRF) ? src[k * H + col] : 0.f;
        float v1 = (k + 1 < NBRF) ? src[(k + 1) * H + col] : 0.f;
        w3t[e] = pk2(v0, v1);
    } else if (e < 73728) {
        int e2 = e - 24576;
        int mat = e2 >> 13;
        int rem = e2 & 8191;
        int col = rem >> 5, kp = rem & 31, k = kp * 2;
        const float* src = (mat >= 3 ? convW_B : convW_A) + (size_t)(mat % 3) * (2 * F + NBRF) * H;
        float v0, v1;
        if (col < 128) { v0 = src[k * H + col];              v1 = src[(k + 1) * H + col]; }
        else           { v0 = src[(64 + k) * H + col - 128]; v1 = src[(64 + k + 1) * H + col - 128]; }
        unsigned short h0 = f2bf(v0), h1 = f2bf(v1);
        w12h[e2] = (unsigned)h0 | ((unsigned)h1 << 16);
        w12l[e2] = (unsigned)f2bf(v0 - bf2f(h0)) | ((unsigned)f2bf(v1 - bf2f(h1)) << 16);
    } else {
        int e3 = e - 73728;
        int br = e3 / 3072;
        int rem = e3 - br * 3072;
        int col = rem / 48, kp = rem - col * 48, k = kp * 2;
        const float* src = br ? embWB : embWA;
        float v0 = (k < ORIG) ? src[k * F + col] : 0.f;
        float v1 = (k + 1 < ORIG) ? src[(k + 1) * F + col] : 0.f;
        unsigned short h0 = f2bf(v0), h1 = f2bf(v1);
        embh[e3] = (unsigned)h0 | ((unsigned)h1 << 16);
        embl[e3] = (unsigned)f2bf(v0 - bf2f(h0)) | ((unsigned)f2bf(v1 - bf2f(h1)) << 16);
    }
}

// ------- nbrcvt -------
__global__ __launch_bounds__(256) void k_nbrcvt(const float* __restrict__ nbrA,
                                                const float* __restrict__ nbrB,
                                                uint4* __restrict__ out) {
    int e = blockIdx.x * 256 + threadIdx.x;
    int row = e / 6, sub = e - row * 6;
    int br = row >= NATOM * MNBR;
    const float* s = (br ? nbrB : nbrA) + (size_t)(row - br * NATOM * MNBR) * NBRF;
    int k0 = sub * 8;
    float v[8];
#pragma unroll
    for (int j = 0; j < 8; ++j) v[j] = (k0 + j < NBRF) ? s[k0 + j] : 0.f;
    uint4 o;
    o.x = pk2(v[0], v[1]);
    o.y = pk2(v[2], v[3]);
    o.z = pk2(v[4], v[5]);
    o.w = pk2(v[6], v[7]);
    out[e] = o;
}

// ------- embed: MFMA hi/lo; writes packed aP -------
__global__ __launch_bounds__(256) void k_embed(const float* __restrict__ atomA,
                                               const float* __restrict__ atomB,
                                               const unsigned* __restrict__ embh,
                                               const unsigned* __restrict__ embl,
                                               const float* __restrict__ embbA,
                                               const float* __restrict__ embbB,
                                               unsigned* __restrict__ aP) {
    __shared__ __align__(16) unsigned short sH[32 * 104];
    __shared__ __align__(16) unsigned short sL[32 * 104];
    int t = threadIdx.x;
    int atom0 = blockIdx.x * 32;
    int br = atom0 >= NATOM;
    const float* src = (br ? atomB : atomA) + (size_t)(atom0 - br * NATOM) * ORIG;

#pragma unroll
    for (int it = 0; it < 3; ++it) {
        int idx = t + it * 256;
        if (idx < 736) {
            int row = idx / 23, sub = idx - row * 23;
            float4 v = *(const float4*)(src + (size_t)row * ORIG + sub * 4);
            int o = row * 104 + sub * 4;
            unsigned short h0 = f2bf(v.x), h1 = f2bf(v.y), h2 = f2bf(v.z), h3 = f2bf(v.w);
            *(uint2*)(sH + o) = uint2{(unsigned)h0 | ((unsigned)h1 << 16),
                                      (unsigned)h2 | ((unsigned)h3 << 16)};
            *(uint2*)(sL + o) = uint2{(unsigned)f2bf(v.x - bf2f(h0)) | ((unsigned)f2bf(v.y - bf2f(h1)) << 16),
                                      (unsigned)f2bf(v.z - bf2f(h2)) | ((unsigned)f2bf(v.w - bf2f(h3)) << 16)};
        } else if (idx < 768) {
            int row = idx - 736;
            *(uint2*)(sH + row * 104 + 92) = uint2{0, 0};
            *(uint2*)(sL + row * 104 + 92) = uint2{0, 0};
        }
    }

    int w = t >> 6, lane = t & 63;
    int lr = lane & 15, lq = lane >> 4;
    int col = w * 16 + lr;

    const unsigned short* bh_base = (const unsigned short*)embh + (size_t)br * 6144 + (size_t)col * 96;
    const unsigned short* bl_base = (const unsigned short*)embl + (size_t)br * 6144 + (size_t)col * 96;
    short8 bh[3], bl[3];
#pragma unroll
    for (int ks = 0; ks < 3; ++ks) {
        bh[ks] = *(const short8*)(bh_base + ks * 32 + lq * 8);
        bl[ks] = *(const short8*)(bl_base + ks * 32 + lq * 8);
    }
    __syncthreads();

    f32x4 acc[2];
    acc[0] = f32x4{0.f, 0.f, 0.f, 0.f};
    acc[1] = f32x4{0.f, 0.f, 0.f, 0.f};
#pragma unroll
    for (int ks = 0; ks < 3; ++ks) {
        int ko = ks * 32 + lq * 8;
        short8 ah[2], al[2];
#pragma unroll
        for (int r = 0; r < 2; ++r) {
            ah[r] = *(const short8*)(sH + (r * 16 + lr) * 104 + ko);
            al[r] = *(const short8*)(sL + (r * 16 + lr) * 104 + ko);
        }
#pragma unroll
        for (int r = 0; r < 2; ++r) {
            acc[r] = __builtin_amdgcn_mfma_f32_16x16x32_bf16(ah[r], bh[ks], acc[r], 0, 0, 0);
            acc[r] = __builtin_amdgcn_mfma_f32_16x16x32_bf16(ah[r], bl[ks], acc[r], 0, 0, 0);
            acc[r] = __builtin_amdgcn_mfma_f32_16x16x32_bf16(al[r], bh[ks], acc[r], 0, 0, 0);
        }
    }

    float bias = (br ? embbB : embbA)[col];
#pragma unroll
    for (int r = 0; r < 2; ++r)
#pragma unroll
        for (int q = 0; q < 4; ++q) {
            int atom = atom0 + r * 16 + lq * 4 + q;
            float val = acc[r][q] + bias;
            unsigned short h = f2bf(val);
            aP[(size_t)atom * F + col] = (unsigned)h | ((unsigned)f2bf(val - bf2f(h)) << 16);
        }
}

// ------- y12: reads packed aP, writes packed y1p/y2p -------
__global__ __launch_bounds__(256, 2) void k_y12(const unsigned* __restrict__ aP,
                                                const unsigned* __restrict__ w12h_base,
                                                const unsigned* __restrict__ w12l_base,
                                                int layer,
                                                unsigned short* __restrict__ y1u,
                                                unsigned short* __restrict__ y2u) {
    __shared__ __align__(16) unsigned short sH[32 * 72];
    __shared__ __align__(16) unsigned short sL[32 * 72];
    int t = threadIdx.x;
    int atom0 = blockIdx.x * 32;
    int br = atom0 >= NATOM;
    int mat = br * 3 + layer;
    const unsigned short* w12h = (const unsigned short*)(w12h_base + (size_t)mat * 8192);
    const unsigned short* w12l = (const unsigned short*)(w12l_base + (size_t)mat * 8192);
#pragma unroll
    for (int it = 0; it < 2; ++it) {
        int c = t + it * 256;
        int row = c >> 4, sub = c & 15;
        uint4 u = *(const uint4*)(aP + (size_t)(atom0 + row) * 64 + sub * 4);
        *(uint2*)(sH + row * 72 + sub * 4) = uint2{packlo(u.x, u.y), packlo(u.z, u.w)};
        *(uint2*)(sL + row * 72 + sub * 4) = uint2{packhi(u.x, u.y), packhi(u.z, u.w)};
    }
    int w = t >> 6, lane = t & 63;
    int lr = lane & 15, lq = lane >> 4;

    short8 bh[2][4], bl[2][4];
#pragma unroll
    for (int kstep = 0; kstep < 2; ++kstep)
#pragma unroll
        for (int n = 0; n < 4; ++n) {
            int col = w * 64 + n * 16 + lr;
            size_t off = (size_t)col * 64 + kstep * 32 + lq * 8;
            bh[kstep][n] = *(const short8*)(w12h + off);
            bl[kstep][n] = *(const short8*)(w12l + off);
        }
    __syncthreads();

    f32x4 acc[4][2];
#pragma unroll
    for (int n = 0; n < 4; ++n)
#pragma unroll
        for (int r = 0; r < 2; ++r) acc[n][r] = f32x4{0.f, 0.f, 0.f, 0.f};

#pragma unroll
    for (int kstep = 0; kstep < 2; ++kstep) {
        int ks = kstep * 32 + lq * 8;
        short8 ah[2], al[2];
#pragma unroll
        for (int r = 0; r < 2; ++r) {
            ah[r] = *(const short8*)(sH + (r * 16 + lr) * 72 + ks);
            al[r] = *(const short8*)(sL + (r * 16 + lr) * 72 + ks);
        }
#pragma unroll
        for (int n = 0; n < 4; ++n)
#pragma unroll
            for (int r = 0; r < 2; ++r) {
                acc[n][r] = __builtin_amdgcn_mfma_f32_16x16x32_bf16(ah[r], bh[kstep][n], acc[n][r], 0, 0, 0);
                acc[n][r] = __builtin_amdgcn_mfma_f32_16x16x32_bf16(ah[r], bl[kstep][n], acc[n][r], 0, 0, 0);
                acc[n][r] = __builtin_amdgcn_mfma_f32_16x16x32_bf16(al[r], bh[kstep][n], acc[n][r], 0, 0, 0);
            }
    }

#pragma unroll
    for (int n = 0; n < 4; ++n) {
        int c = w * 64 + n * 16 + lr;
        int cc = c & 127;
        int p = cc >> 6, cb = cc & 63;
        unsigned short* base = (c < 128) ? y1u : y2u;
        unsigned short* dst = base + cb * 2 + p;
#pragma unroll
        for (int r = 0; r < 2; ++r)
#pragma unroll
            for (int q = 0; q < 4; ++q) {
                int atom = atom0 + r * 16 + lq * 4 + q;
                dst[(size_t)atom * 128] = f2h(acc[n][r][q]);
            }
    }
}

// ------- conv: filt/core paired cols, in-register epilogue -------
// LDS: sA 48x144B=6912 | sS1 512 | sH1 512 | sS2 256 | sH2 256 | sp 12x65x4=3120 | sJ 192
__global__ __launch_bounds__(256, 6) void k_convfused(
        const unsigned* __restrict__ y1p,
        const unsigned* __restrict__ y2p,
        const unsigned short* __restrict__ nbrb,
        const int* __restrict__ idxA, const int* __restrict__ idxB,
        const unsigned* __restrict__ w3t, int layer,
        const float* __restrict__ biasA, const float* __restrict__ biasB,
        const float* __restrict__ bn1A,  const float* __restrict__ bn1B,
        const float* __restrict__ bn2A,  const float* __restrict__ bn2B,
        unsigned* __restrict__ aP) {
    __shared__ __align__(16) unsigned char sAbuf[6912];
    __shared__ float sS1[128], sH1[128], sS2[64], sH2[64];
    __shared__ float sp[12 * 65 + 3];   // padded rows (65 floats) -> conflict-free
    __shared__ __align__(16) int sJ[48];

    int t = threadIdx.x;
    int atom0 = blockIdx.x * 4;
    int br = atom0 >= NATOM;
    int brOff = br * NATOM;
    int R0 = atom0 * MNBR;
    const float* bias = br ? biasB : biasA;
    const float* bn1  = br ? bn1B : bn1A;
    const float* bn2  = br ? bn2B : bn2A;
    const unsigned short* w3l = (const unsigned short*)(w3t + (size_t)(br * 3 + layer) * 4096);

    // stage A: 288 data chunks + 96 k-tail zero chunks
#pragma unroll
    for (int j = 0; j < 2; ++j) {
        int c = t + j * 256;
        if (c < 288) {
            int row = c / 6, sub = c - row * 6;
            short8 v = *(const short8*)(nbrb + (size_t)(R0 + row) * 48 + sub * 8);
            *(short8*)(sAbuf + row * 144 + sub * 16) = v;
        } else if (c < 384) {
            int z = c - 288;
            int row = z >> 1, sub = 6 + (z & 1);
            *(short8*)(sAbuf + row * 144 + sub * 16) = short8{0, 0, 0, 0, 0, 0, 0, 0};
        }
    }
    if (t < 128) {
        float g = bn1[t], be = bn1[128 + t], mu = bn1[256 + t], va = bn1[384 + t];
        float s = g * rsqrtf(va + 1e-5f);
        sS1[t] = s;
        sH1[t] = be - mu * s + bias[t] * s;
    } else if (t < 192) {
        int u = t - 128;
        float g = bn2[u], be = bn2[64 + u], mu = bn2[128 + u], va = bn2[192 + u];
        float s = g * rsqrtf(va + 1e-5f);
        sS2[u] = s;
        sH2[u] = be - mu * s;
    }
    if (t < 48) sJ[t] = ((br ? idxB : idxA) + (size_t)(atom0 - brOff) * MNBR)[t];

    int w = t >> 6, lane = t & 63;
    int lr = lane & 15, lq = lane >> 4;
    int f = w * 16 + lr;                  // this lane's feature (0..63)

    // B frags: n=0 -> filt col f ; n=1 -> core col 64+f
    short8 bfr[2][2];
#pragma unroll
    for (int kstep = 0; kstep < 2; ++kstep) {
        int ks = kstep * 32 + lq * 8;
        bfr[kstep][0] = *(const short8*)(w3l + (size_t)f * 64 + ks);
        bfr[kstep][1] = *(const short8*)(w3l + (size_t)(64 + f) * 64 + ks);
    }
    __syncthreads();

    f32x4 acc[2][3];
#pragma unroll
    for (int n = 0; n < 2; ++n)
#pragma unroll
        for (int r = 0; r < 3; ++r) acc[n][r] = f32x4{0.f, 0.f, 0.f, 0.f};

#pragma unroll
    for (int kstep = 0; kstep < 2; ++kstep) {
        int ks = kstep * 32 + lq * 8;
        short8 af[3];
#pragma unroll
        for (int r = 0; r < 3; ++r) {
            int row = r * 16 + lr;
            af[r] = *(const short8*)(sAbuf + (size_t)row * 144 + ks * 2);
        }
#pragma unroll
        for (int n = 0; n < 2; ++n)
#pragma unroll
            for (int r = 0; r < 3; ++r)
                acc[n][r] = __builtin_amdgcn_mfma_f32_16x16x32_bf16(af[r], bfr[kstep][n], acc[n][r], 0, 0, 0);
    }

    // in-register epilogue: lane holds zf (acc[0]) and zc (acc[1]) for feature f
    float s1f = sS1[f], h1f = sH1[f], s1c = sS1[64 + f], h1c = sH1[64 + f];
#pragma unroll
    for (int r = 0; r < 3; ++r) {
        int rowbase = 16 * r + 4 * lq;
        int4 jq = *(const int4*)(sJ + rowbase);      // j for rows rowbase..+3 (one atom)
        int atom = (4 * r + lq) / 3;                 // 4-row group lies in one atom
        unsigned y1v = y1p[(size_t)(atom0 + atom) * 64 + f];
        float y1f = h2f((unsigned short)(y1v & 0xffff));
        float y1c = h2f((unsigned short)(y1v >> 16));
        float partial = 0.f;
        unsigned g0 = y2p[(size_t)(jq.x + brOff) * 64 + f];
        unsigned g1 = y2p[(size_t)(jq.y + brOff) * 64 + f];
        unsigned g2 = y2p[(size_t)(jq.z + brOff) * 64 + f];
        unsigned g3 = y2p[(size_t)(jq.w + brOff) * 64 + f];
        unsigned gv[4] = {g0, g1, g2, g3};
#pragma unroll
        for (int q = 0; q < 4; ++q) {
            float zf = (acc[0][r][q] + y1f + h2f((unsigned short)(gv[q] & 0xffff))) * s1f + h1f;
            float zc = (acc[1][r][q] + y1c + h2f((unsigned short)(gv[q] >> 16))) * s1c + h1c;
            partial += sigmoidf(zf) * softplusf(zc);
        }
        sp[(4 * r + lq) * 65 + f] = partial;
    }
    __syncthreads();

    // final: thread (al, f2) sums the atom's 3 partial groups, residual+BN2
    int al = t >> 6, f2 = t & 63;
    float sacc = sp[(3 * al + 0) * 65 + f2] + sp[(3 * al + 1) * 65 + f2] + sp[(3 * al + 2) * 65 + f2];
    size_t o = (size_t)(atom0 + al) * 64 + f2;
    unsigned au = aP[o];
    float av = bf2f((unsigned short)(au & 0xffff)) + bf2f((unsigned short)(au >> 16));
    float res = softplusf(av + sacc * sS2[f2] + sH2[f2]);
    unsigned short hh = f2bf(res);
    aP[o] = (unsigned)hh | ((unsigned)f2bf(res - bf2f(hh)) << 16);
}

// ------- pool: packed aP, 4-atom groups -------
__global__ __launch_bounds__(256) void k_pool(const unsigned* __restrict__ aP,
                                              const int* __restrict__ segA,
                                              const int* __restrict__ segB,
                                              float* __restrict__ poolU,
                                              float* __restrict__ cntU) {
    int t = threadIdx.x;
    int f = t & 63, g = t >> 6;
    int n0 = blockIdx.x * 16 + g * 4;
    int br = n0 >= NATOM;
    const int* seg = br ? segB : segA;
    int nl = n0 - br * NATOM;
    int s0 = seg[nl], s1 = seg[nl + 1], s2 = seg[nl + 2], s3 = seg[nl + 3];
    unsigned u0 = aP[(size_t)(n0 + 0) * F + f];
    unsigned u1 = aP[(size_t)(n0 + 1) * F + f];
    unsigned u2 = aP[(size_t)(n0 + 2) * F + f];
    unsigned u3 = aP[(size_t)(n0 + 3) * F + f];
    float v0 = bf2f((unsigned short)(u0 & 0xffff)) + bf2f((unsigned short)(u0 >> 16));
    float v1 = bf2f((unsigned short)(u1 & 0xffff)) + bf2f((unsigned short)(u1 >> 16));
    float v2 = bf2f((unsigned short)(u2 & 0xffff)) + bf2f((unsigned short)(u2 >> 16));
    float v3 = bf2f((unsigned short)(u3 & 0xffff)) + bf2f((unsigned short)(u3 >> 16));
    int cOff = br * NCRYS;
    if (s0 == s3) {
        atomicAdd(&poolU[(size_t)(s0 + cOff) * F + f], v0 + v1 + v2 + v3);
        if (f == 0) atomicAdd(&cntU[s0 + cOff], 4.f);
    } else {
        atomicAdd(&poolU[(size_t)(s0 + cOff) * F + f], v0);
        atomicAdd(&poolU[(size_t)(s1 + cOff) * F + f], v1);
        atomicAdd(&poolU[(size_t)(s2 + cOff) * F + f], v2);
        atomicAdd(&poolU[(size_t)(s3 + cOff) * F + f], v3);
        if (f == 0) {
            atomicAdd(&cntU[s0 + cOff], 1.f);
            atomicAdd(&cntU[s1 + cOff], 1.f);
            atomicAdd(&cntU[s2 + cOff], 1.f);
            atomicAdd(&cntU[s3 + cOff], 1.f);
        }
    }
}

// ------- head -------
__global__ __launch_bounds__(128) void k_head(const float* __restrict__ poolU,
                                              const float* __restrict__ cntU,
                                              const float* __restrict__ denWA,
                                              const float* __restrict__ denbA,
                                              const float* __restrict__ denWB,
                                              const float* __restrict__ denbB,
                                              const float* __restrict__ ffW,
                                              const float* __restrict__ ffb,
                                              const float* __restrict__ outW,
                                              const float* __restrict__ outb,
                                              float* __restrict__ out) {
    int c = blockIdx.x;
    int h = threadIdx.x;
    __shared__ float spA[F], spB[F], sd[H], st[H];
    if (h < F) spA[h] = poolU[(size_t)c * F + h] / fmaxf(cntU[c], 1.f);
    else {
        int u = h - F;
        spB[u] = poolU[(size_t)(c + NCRYS) * F + u] / fmaxf(cntU[c + NCRYS], 1.f);
    }
    __syncthreads();
    float accA = denbA[h], accB = denbB[h];
#pragma unroll
    for (int k = 0; k < F; ++k) {
        accA = fmaf(spA[k], denWA[k * H + h], accA);
        accB = fmaf(spB[k], denWB[k * H + h], accB);
    }
    sd[h] = fabsf(softplusf(accA) - softplusf(accB));
    __syncthreads();
    float acc = ffb[h];
#pragma unroll
    for (int k = 0; k < H; ++k) acc = fmaf(sd[k], ffW[k * H + h], acc);
    st[h] = softplusf(acc) * outW[h];
    __syncthreads();
    for (int s = 64; s > 0; s >>= 1) {
        if (h < s) st[h] += st[h + s];
        __syncthreads();
    }
    if (h == 0) out[c] = st[0] + outb[0];
}

extern "C" void kernel_launch(void* const* d_in, const int* in_sizes, int n_in,
                              void* d_out, int out_size, void* d_ws, size_t ws_size,
                              hipStream_t stream) {
    const float* atomA = (const float*)d_in[0];
    const float* nbrA  = (const float*)d_in[1];
    const int*   idxA  = (const int*)d_in[2];
    const int*   segA  = (const int*)d_in[3];
    const float* embWA = (const float*)d_in[4];
    const float* embbA = (const float*)d_in[5];
    const float* convWA = (const float*)d_in[6];
    const float* convbA = (const float*)d_in[7];
    const float* bn1A  = (const float*)d_in[8];
    const float* bn2A  = (const float*)d_in[9];
    const float* denWA = (const float*)d_in[10];
    const float* denbA = (const float*)d_in[11];
    const float* atomB = (const float*)d_in[12];
    const float* nbrB  = (const float*)d_in[13];
    const int*   idxB  = (const int*)d_in[14];
    const int*   segB  = (const int*)d_in[15];
    const float* embWB = (const float*)d_in[16];
    const float* embbB = (const float*)d_in[17];
    const float* convWB = (const float*)d_in[18];
    const float* convbB = (const float*)d_in[19];
    const float* bn1B  = (const float*)d_in[20];
    const float* bn2B  = (const float*)d_in[21];
    const float* denWB = (const float*)d_in[22];
    const float* denbB = (const float*)d_in[23];
    const float* ffW   = (const float*)d_in[24];
    const float* ffb   = (const float*)d_in[25];
    const float* outW  = (const float*)d_in[26];
    const float* outb  = (const float*)d_in[27];

    unsigned* y1p = (unsigned*)d_ws;
    unsigned* y2p = y1p + (size_t)2 * NATOM * 64;
    float* poolU = (float*)(y2p + (size_t)2 * NATOM * 64);
    float* cntU  = poolU + 2 * NCRYS * F;
    unsigned* w3t  = (unsigned*)(cntU + 2 * NCRYS);
    unsigned* w12h = w3t + 24576;
    unsigned* w12l = w12h + 49152;
    unsigned* embh = w12l + 49152;
    unsigned* embl = embh + 6144;
    unsigned* nbrb = embl + 6144;
    unsigned* aP   = nbrb + (size_t)2 * NATOM * MNBR * 24;

    hipMemsetAsync(poolU, 0, (size_t)(2 * NCRYS * F + 2 * NCRYS) * sizeof(float), stream);
    k_wcvt<<<312, 256, 0, stream>>>(convWA, convWB, embWA, embWB, w3t, w12h, w12l, embh, embl);
    k_nbrcvt<<<2 * NATOM * MNBR * 6 / 256, 256, 0, stream>>>(nbrA, nbrB, (uint4*)nbrb);
    k_embed<<<2 * NATOM / 32, 256, 0, stream>>>(atomA, atomB, embh, embl, embbA, embbB, aP);
    for (int l = 0; l < NCONV; ++l) {
        k_y12<<<2 * NATOM / 32, 256, 0, stream>>>(aP, w12h, w12l, l,
                                                  (unsigned short*)y1p, (unsigned short*)y2p);
        k_convfused<<<2 * NATOM / 4, 256, 0, stream>>>(
            y1p, y2p, (const unsigned short*)nbrb, idxA, idxB, w3t, l,
            convbA + l * H, convbB + l * H,
            bn1A + l * 4 * H, bn1B + l * 4 * H,
            bn2A + l * 4 * F, bn2B + l * 4 * F,
            aP);
    }
    k_pool<<<2 * NATOM * F / (256 * 4), 256, 0, stream>>>(aP, segA, segB, poolU, cntU);
    k_head<<<NCRYS, 128, 0, stream>>>(poolU, cntU, denWA, denbA, denWB, denbB,
                                      ffW, ffb, outW, outb, (float*)d_out);
}

// Round 14
// 237.882 us; speedup vs baseline: 1.0512x; 1.0512x over previous
//
#include <hip/hip_runtime.h>

// Paired CGCNN (separated) — R14.
// R14 vs R13 (no arithmetic change):
//  - k_convfused: 32-bit voffset addressing (branch-uniform SGPR bases),
//    div-free staging (48 rows x 8 chunks, row=c>>3; pad bytes never written).
//  - k_nbrcvt: LDS-recoalesced (64 rows staged via float4, contiguous uint4 out).

constexpr int NATOM = 20000;
constexpr int MNBR  = 12;
constexpr int ORIG  = 92;
constexpr int NBRF  = 41;
constexpr int F     = 64;
constexpr int H     = 128;
constexpr int NCONV = 3;
constexpr int NCRYS = 400;

#define DEVFN __device__ __forceinline__

typedef __attribute__((ext_vector_type(8))) short short8;
typedef __attribute__((ext_vector_type(4))) float f32x4;

DEVFN float softplusf(float x) {
    return fmaxf(x, 0.f) + __logf(1.f + __expf(-fabsf(x)));
}
DEVFN float sigmoidf(float x) {
    return __builtin_amdgcn_rcpf(1.f + __expf(-x));
}
DEVFN unsigned short f2bf(float x) {
    union { float f; unsigned u; } v{x};
    unsigned r = v.u + 0x7FFF + ((v.u >> 16) & 1);
    return (unsigned short)(r >> 16);
}
DEVFN float bf2f(unsigned short h) {
    union { unsigned u; float f; } v;
    v.u = (unsigned)h << 16;
    return v.f;
}
DEVFN unsigned pk2(float a, float b) {
    return (unsigned)f2bf(a) | ((unsigned)f2bf(b) << 16);
}
DEVFN unsigned short f2h(float x) {
    _Float16 h = (_Float16)x;
    union { _Float16 h; unsigned short u; } v{h};
    return v.u;
}
DEVFN float h2f(unsigned short u) {
    union { unsigned short u; _Float16 h; } v{u};
    return (float)v.h;
}
DEVFN unsigned packlo(unsigned a, unsigned b) { return (a & 0xffffu) | (b << 16); }
DEVFN unsigned packhi(unsigned a, unsigned b) { return (a >> 16) | (b & 0xffff0000u); }

// ------- wcvt -------
__global__ __launch_bounds__(256) void k_wcvt(const float* __restrict__ convW_A,
                                              const float* __restrict__ convW_B,
                                              const float* __restrict__ embWA,
                                              const float* __restrict__ embWB,
                                              unsigned* __restrict__ w3t,
                                              unsigned* __restrict__ w12h,
                                              unsigned* __restrict__ w12l,
                                              unsigned* __restrict__ embh,
                                              unsigned* __restrict__ embl) {
    int e = blockIdx.x * 256 + threadIdx.x;
    if (e < 24576) {
        int mat = e >> 12;
        int rem = e & 4095;
        int col = rem >> 5, kp = rem & 31, k = kp * 2;
        int br = mat / 3, l = mat - br * 3;
        const float* src = (br ? convW_B : convW_A) + (size_t)l * (2 * F + NBRF) * H + 128 * H;
        float v0 = (k < NBRF) ? src[k * H + col] : 0.f;
        float v1 = (k + 1 < NBRF) ? src[(k + 1) * H + col] : 0.f;
        w3t[e] = pk2(v0, v1);
    } else if (e < 73728) {
        int e2 = e - 24576;
        int mat = e2 >> 13;
        int rem = e2 & 8191;
        int col = rem >> 5, kp = rem & 31, k = kp * 2;
        const float* src = (mat >= 3 ? convW_B : convW_A) + (size_t)(mat % 3) * (2 * F + NBRF) * H;
        float v0, v1;
        if (col < 128) { v0 = src[k * H + col];              v1 = src[(k + 1) * H + col]; }
        else           { v0 = src[(64 + k) * H + col - 128]; v1 = src[(64 + k + 1) * H + col - 128]; }
        unsigned short h0 = f2bf(v0), h1 = f2bf(v1);
        w12h[e2] = (unsigned)h0 | ((unsigned)h1 << 16);
        w12l[e2] = (unsigned)f2bf(v0 - bf2f(h0)) | ((unsigned)f2bf(v1 - bf2f(h1)) << 16);
    } else {
        int e3 = e - 73728;
        int br = e3 / 3072;
        int rem = e3 - br * 3072;
        int col = rem / 48, kp = rem - col * 48, k = kp * 2;
        const float* src = br ? embWB : embWA;
        float v0 = (k < ORIG) ? src[k * F + col] : 0.f;
        float v1 = (k + 1 < ORIG) ? src[(k + 1) * F + col] : 0.f;
        unsigned short h0 = f2bf(v0), h1 = f2bf(v1);
        embh[e3] = (unsigned)h0 | ((unsigned)h1 << 16);
        embl[e3] = (unsigned)f2bf(v0 - bf2f(h0)) | ((unsigned)f2bf(v1 - bf2f(h1)) << 16);
    }
}

// ------- nbrcvt v2: LDS-recoalesced; 64 rows/block -------
__global__ __launch_bounds__(256) void k_nbrcvt(const float* __restrict__ nbrA,
                                                const float* __restrict__ nbrB,
                                                uint4* __restrict__ out) {
    __shared__ __align__(16) float sIn[64 * NBRF];   // 10496 B
    int t = threadIdx.x;
    int b = blockIdx.x;                  // 7500 blocks; 3750 per branch
    int br = b >= 3750;
    int lrow0 = (b - br * 3750) * 64;
    const float4* src4 = (const float4*)((br ? nbrB : nbrA) + (size_t)lrow0 * NBRF);
#pragma unroll
    for (int it = 0; it < 3; ++it) {
        int e = t + it * 256;
        if (e < 656) ((float4*)sIn)[e] = src4[e];
    }
    __syncthreads();
    int grow0 = br * (NATOM * MNBR) + lrow0;
    uint4* dst = out + (size_t)grow0 * 6;
#pragma unroll
    for (int it = 0; it < 2; ++it) {
        int c = t + it * 256;
        if (c < 384) {
            int row = c / 6, sub = c - row * 6;
            const float* s = sIn + row * NBRF;
            int k0 = sub * 8;
            float v[8];
#pragma unroll
            for (int j = 0; j < 8; ++j) v[j] = (k0 + j < NBRF) ? s[k0 + j] : 0.f;
            uint4 o;
            o.x = pk2(v[0], v[1]);
            o.y = pk2(v[2], v[3]);
            o.z = pk2(v[4], v[5]);
            o.w = pk2(v[6], v[7]);
            dst[c] = o;
        }
    }
}

// ------- embed: MFMA hi/lo; writes packed aP -------
__global__ __launch_bounds__(256) void k_embed(const float* __restrict__ atomA,
                                               const float* __restrict__ atomB,
                                               const unsigned* __restrict__ embh,
                                               const unsigned* __restrict__ embl,
                                               const float* __restrict__ embbA,
                                               const float* __restrict__ embbB,
                                               unsigned* __restrict__ aP) {
    __shared__ __align__(16) unsigned short sH[32 * 104];
    __shared__ __align__(16) unsigned short sL[32 * 104];
    int t = threadIdx.x;
    int atom0 = blockIdx.x * 32;
    int br = atom0 >= NATOM;
    const float* src = (br ? atomB : atomA) + (size_t)(atom0 - br * NATOM) * ORIG;

#pragma unroll
    for (int it = 0; it < 3; ++it) {
        int idx = t + it * 256;
        if (idx < 736) {
            int row = idx / 23, sub = idx - row * 23;
            float4 v = *(const float4*)(src + (size_t)row * ORIG + sub * 4);
            int o = row * 104 + sub * 4;
            unsigned short h0 = f2bf(v.x), h1 = f2bf(v.y), h2 = f2bf(v.z), h3 = f2bf(v.w);
            *(uint2*)(sH + o) = uint2{(unsigned)h0 | ((unsigned)h1 << 16),
                                      (unsigned)h2 | ((unsigned)h3 << 16)};
            *(uint2*)(sL + o) = uint2{(unsigned)f2bf(v.x - bf2f(h0)) | ((unsigned)f2bf(v.y - bf2f(h1)) << 16),
                                      (unsigned)f2bf(v.z - bf2f(h2)) | ((unsigned)f2bf(v.w - bf2f(h3)) << 16)};
        } else if (idx < 768) {
            int row = idx - 736;
            *(uint2*)(sH + row * 104 + 92) = uint2{0, 0};
            *(uint2*)(sL + row * 104 + 92) = uint2{0, 0};
        }
    }

    int w = t >> 6, lane = t & 63;
    int lr = lane & 15, lq = lane >> 4;
    int col = w * 16 + lr;

    const unsigned short* bh_base = (const unsigned short*)embh + (size_t)br * 6144 + (size_t)col * 96;
    const unsigned short* bl_base = (const unsigned short*)embl + (size_t)br * 6144 + (size_t)col * 96;
    short8 bh[3], bl[3];
#pragma unroll
    for (int ks = 0; ks < 3; ++ks) {
        bh[ks] = *(const short8*)(bh_base + ks * 32 + lq * 8);
        bl[ks] = *(const short8*)(bl_base + ks * 32 + lq * 8);
    }
    __syncthreads();

    f32x4 acc[2];
    acc[0] = f32x4{0.f, 0.f, 0.f, 0.f};
    acc[1] = f32x4{0.f, 0.f, 0.f, 0.f};
#pragma unroll
    for (int ks = 0; ks < 3; ++ks) {
        int ko = ks * 32 + lq * 8;
        short8 ah[2], al[2];
#pragma unroll
        for (int r = 0; r < 2; ++r) {
            ah[r] = *(const short8*)(sH + (r * 16 + lr) * 104 + ko);
            al[r] = *(const short8*)(sL + (r * 16 + lr) * 104 + ko);
        }
#pragma unroll
        for (int r = 0; r < 2; ++r) {
            acc[r] = __builtin_amdgcn_mfma_f32_16x16x32_bf16(ah[r], bh[ks], acc[r], 0, 0, 0);
            acc[r] = __builtin_amdgcn_mfma_f32_16x16x32_bf16(ah[r], bl[ks], acc[r], 0, 0, 0);
            acc[r] = __builtin_amdgcn_mfma_f32_16x16x32_bf16(al[r], bh[ks], acc[r], 0, 0, 0);
        }
    }

    float bias = (br ? embbB : embbA)[col];
#pragma unroll
    for (int r = 0; r < 2; ++r)
#pragma unroll
        for (int q = 0; q < 4; ++q) {
            int atom = atom0 + r * 16 + lq * 4 + q;
            float val = acc[r][q] + bias;
            unsigned short h = f2bf(val);
            aP[(unsigned)(atom * F + col)] = (unsigned)h | ((unsigned)f2bf(val - bf2f(h)) << 16);
        }
}

// ------- y12: reads packed aP, writes packed y1p/y2p -------
__global__ __launch_bounds__(256, 2) void k_y12(const unsigned* __restrict__ aP,
                                                const unsigned* __restrict__ w12h_base,
                                                const unsigned* __restrict__ w12l_base,
                                                int layer,
                                                unsigned short* __restrict__ y1u,
                                                unsigned short* __restrict__ y2u) {
    __shared__ __align__(16) unsigned short sH[32 * 72];
    __shared__ __align__(16) unsigned short sL[32 * 72];
    int t = threadIdx.x;
    int atom0 = blockIdx.x * 32;
    int br = atom0 >= NATOM;
    int mat = br * 3 + layer;
    const unsigned short* w12h = (const unsigned short*)(w12h_base + (size_t)mat * 8192);
    const unsigned short* w12l = (const unsigned short*)(w12l_base + (size_t)mat * 8192);
#pragma unroll
    for (int it = 0; it < 2; ++it) {
        int c = t + it * 256;
        int row = c >> 4, sub = c & 15;
        uint4 u = *(const uint4*)(aP + (unsigned)((atom0 + row) * 64 + sub * 4));
        *(uint2*)(sH + row * 72 + sub * 4) = uint2{packlo(u.x, u.y), packlo(u.z, u.w)};
        *(uint2*)(sL + row * 72 + sub * 4) = uint2{packhi(u.x, u.y), packhi(u.z, u.w)};
    }
    int w = t >> 6, lane = t & 63;
    int lr = lane & 15, lq = lane >> 4;

    short8 bh[2][4], bl[2][4];
#pragma unroll
    for (int kstep = 0; kstep < 2; ++kstep)
#pragma unroll
        for (int n = 0; n < 4; ++n) {
            int col = w * 64 + n * 16 + lr;
            size_t off = (size_t)col * 64 + kstep * 32 + lq * 8;
            bh[kstep][n] = *(const short8*)(w12h + off);
            bl[kstep][n] = *(const short8*)(w12l + off);
        }
    __syncthreads();

    f32x4 acc[4][2];
#pragma unroll
    for (int n = 0; n < 4; ++n)
#pragma unroll
        for (int r = 0; r < 2; ++r) acc[n][r] = f32x4{0.f, 0.f, 0.f, 0.f};

#pragma unroll
    for (int kstep = 0; kstep < 2; ++kstep) {
        int ks = kstep * 32 + lq * 8;
        short8 ah[2], al[2];
#pragma unroll
        for (int r = 0; r < 2; ++r) {
            ah[r] = *(const short8*)(sH + (r * 16 + lr) * 72 + ks);
            al[r] = *(const short8*)(sL + (r * 16 + lr) * 72 + ks);
        }
#pragma unroll
        for (int n = 0; n < 4; ++n)
#pragma unroll
            for (int r = 0; r < 2; ++r) {
                acc[n][r] = __builtin_amdgcn_mfma_f32_16x16x32_bf16(ah[r], bh[kstep][n], acc[n][r], 0, 0, 0);
                acc[n][r] = __builtin_amdgcn_mfma_f32_16x16x32_bf16(ah[r], bl[kstep][n], acc[n][r], 0, 0, 0);
                acc[n][r] = __builtin_amdgcn_mfma_f32_16x16x32_bf16(al[r], bh[kstep][n], acc[n][r], 0, 0, 0);
            }
    }

#pragma unroll
    for (int n = 0; n < 4; ++n) {
        int c = w * 64 + n * 16 + lr;
        int cc = c & 127;
        int p = cc >> 6, cb = cc & 63;
        unsigned short* base = (c < 128) ? y1u : y2u;
        unsigned short* dst = base + cb * 2 + p;
#pragma unroll
        for (int r = 0; r < 2; ++r)
#pragma unroll
            for (int q = 0; q < 4; ++q) {
                int atom = atom0 + r * 16 + lq * 4 + q;
                dst[(unsigned)(atom * 128)] = f2h(acc[n][r][q]);
            }
    }
}

// ------- conv: filt/core paired cols, in-register epilogue, 32-bit offsets -------
__global__ __launch_bounds__(256, 6) void k_convfused(
        const unsigned* __restrict__ y1p,
        const unsigned* __restrict__ y2p,
        const unsigned short* __restrict__ nbrb,
        const int* __restrict__ idxA, const int* __restrict__ idxB,
        const unsigned* __restrict__ w3t, int layer,
        const float* __restrict__ biasA, const float* __restrict__ biasB,
        const float* __restrict__ bn1A,  const float* __restrict__ bn1B,
        const float* __restrict__ bn2A,  const float* __restrict__ bn2B,
        unsigned* __restrict__ aP) {
    __shared__ __align__(16) unsigned char sAbuf[48 * 144];
    __shared__ float sS1[128], sH1[128], sS2[64], sH2[64];
    __shared__ float sp[12 * 65 + 3];
    __shared__ __align__(16) int sJ[48];

    int t = threadIdx.x;
    int atom0 = blockIdx.x * 4;
    int br = atom0 >= NATOM;
    int brOff = br * NATOM;
    unsigned R0 = (unsigned)atom0 * MNBR;
    const float* bias = br ? biasB : biasA;
    const float* bn1  = br ? bn1B : bn1A;
    const float* bn2  = br ? bn2B : bn2A;
    const unsigned short* w3l = (const unsigned short*)(w3t + (size_t)(br * 3 + layer) * 4096);
    // branch-uniform pre-biased bases (SGPR)
    const unsigned* y2b = y2p + (size_t)brOff * 64;
    const unsigned* y1b = y1p + (size_t)atom0 * 64;
    unsigned* aPb = aP + (size_t)atom0 * 64;

    // stage A: 48 rows x 8 chunks (div-free); chunks 6-7 are the k=48..63 zeros.
    // (row pad bytes 128..143 are never read by MFMA -> never written.)
#pragma unroll
    for (int jj = 0; jj < 2; ++jj) {
        int c = t + jj * 256;
        if (c < 384) {
            int row = c >> 3, sub = c & 7;
            short8 v = short8{0, 0, 0, 0, 0, 0, 0, 0};
            if (sub < 6) v = *(const short8*)(nbrb + ((R0 + row) * 48u + sub * 8u));
            *(short8*)(sAbuf + row * 144 + sub * 16) = v;
        }
    }
    if (t < 128) {
        float g = bn1[t], be = bn1[128 + t], mu = bn1[256 + t], va = bn1[384 + t];
        float s = g * rsqrtf(va + 1e-5f);
        sS1[t] = s;
        sH1[t] = be - mu * s + bias[t] * s;
    } else if (t < 192) {
        int u = t - 128;
        float g = bn2[u], be = bn2[64 + u], mu = bn2[128 + u], va = bn2[192 + u];
        float s = g * rsqrtf(va + 1e-5f);
        sS2[u] = s;
        sH2[u] = be - mu * s;
    }
    if (t < 48) sJ[t] = ((br ? idxB : idxA) + (size_t)(atom0 - brOff) * MNBR)[t];

    int w = t >> 6, lane = t & 63;
    int lr = lane & 15, lq = lane >> 4;
    int f = w * 16 + lr;

    short8 bfr[2][2];
#pragma unroll
    for (int kstep = 0; kstep < 2; ++kstep) {
        int ks = kstep * 32 + lq * 8;
        bfr[kstep][0] = *(const short8*)(w3l + (unsigned)(f * 64 + ks));
        bfr[kstep][1] = *(const short8*)(w3l + (unsigned)((64 + f) * 64 + ks));
    }
    __syncthreads();

    f32x4 acc[2][3];
#pragma unroll
    for (int n = 0; n < 2; ++n)
#pragma unroll
        for (int r = 0; r < 3; ++r) acc[n][r] = f32x4{0.f, 0.f, 0.f, 0.f};

#pragma unroll
    for (int kstep = 0; kstep < 2; ++kstep) {
        int ks = kstep * 32 + lq * 8;
        short8 af[3];
#pragma unroll
        for (int r = 0; r < 3; ++r) {
            int row = r * 16 + lr;
            af[r] = *(const short8*)(sAbuf + row * 144 + ks * 2);
        }
#pragma unroll
        for (int n = 0; n < 2; ++n)
#pragma unroll
            for (int r = 0; r < 3; ++r)
                acc[n][r] = __builtin_amdgcn_mfma_f32_16x16x32_bf16(af[r], bfr[kstep][n], acc[n][r], 0, 0, 0);
    }

    float s1f = sS1[f], h1f = sH1[f], s1c = sS1[64 + f], h1c = sH1[64 + f];
#pragma unroll
    for (int r = 0; r < 3; ++r) {
        int rowbase = 16 * r + 4 * lq;
        int4 jq = *(const int4*)(sJ + rowbase);
        int atom = (4 * r + lq) / 3;
        unsigned y1v = y1b[(unsigned)(atom * 64 + f)];
        float y1f = h2f((unsigned short)(y1v & 0xffff));
        float y1c = h2f((unsigned short)(y1v >> 16));
        unsigned g0 = y2b[(unsigned)jq.x * 64u + (unsigned)f];
        unsigned g1 = y2b[(unsigned)jq.y * 64u + (unsigned)f];
        unsigned g2 = y2b[(unsigned)jq.z * 64u + (unsigned)f];
        unsigned g3 = y2b[(unsigned)jq.w * 64u + (unsigned)f];
        unsigned gv[4] = {g0, g1, g2, g3};
        float partial = 0.f;
#pragma unroll
        for (int q = 0; q < 4; ++q) {
            float zf = (acc[0][r][q] + y1f + h2f((unsigned short)(gv[q] & 0xffff))) * s1f + h1f;
            float zc = (acc[1][r][q] + y1c + h2f((unsigned short)(gv[q] >> 16))) * s1c + h1c;
            partial += sigmoidf(zf) * softplusf(zc);
        }
        sp[(4 * r + lq) * 65 + f] = partial;
    }
    __syncthreads();

    int al = t >> 6, f2 = t & 63;
    float sacc = sp[(3 * al + 0) * 65 + f2] + sp[(3 * al + 1) * 65 + f2] + sp[(3 * al + 2) * 65 + f2];
    unsigned o = (unsigned)(al * 64 + f2);
    unsigned au = aPb[o];
    float av = bf2f((unsigned short)(au & 0xffff)) + bf2f((unsigned short)(au >> 16));
    float res = softplusf(av + sacc * sS2[f2] + sH2[f2]);
    unsigned short hh = f2bf(res);
    aPb[o] = (unsigned)hh | ((unsigned)f2bf(res - bf2f(hh)) << 16);
}

// ------- pool: packed aP, 4-atom groups -------
__global__ __launch_bounds__(256) void k_pool(const unsigned* __restrict__ aP,
                                              const int* __restrict__ segA,
                                              const int* __restrict__ segB,
                                              float* __restrict__ poolU,
                                              float* __restrict__ cntU) {
    int t = threadIdx.x;
    int f = t & 63, g = t >> 6;
    int n0 = blockIdx.x * 16 + g * 4;
    int br = n0 >= NATOM;
    const int* seg = br ? segB : segA;
    int nl = n0 - br * NATOM;
    int s0 = seg[nl], s1 = seg[nl + 1], s2 = seg[nl + 2], s3 = seg[nl + 3];
    unsigned u0 = aP[(unsigned)((n0 + 0) * F + f)];
    unsigned u1 = aP[(unsigned)((n0 + 1) * F + f)];
    unsigned u2 = aP[(unsigned)((n0 + 2) * F + f)];
    unsigned u3 = aP[(unsigned)((n0 + 3) * F + f)];
    float v0 = bf2f((unsigned short)(u0 & 0xffff)) + bf2f((unsigned short)(u0 >> 16));
    float v1 = bf2f((unsigned short)(u1 & 0xffff)) + bf2f((unsigned short)(u1 >> 16));
    float v2 = bf2f((unsigned short)(u2 & 0xffff)) + bf2f((unsigned short)(u2 >> 16));
    float v3 = bf2f((unsigned short)(u3 & 0xffff)) + bf2f((unsigned short)(u3 >> 16));
    int cOff = br * NCRYS;
    if (s0 == s3) {
        atomicAdd(&poolU[(size_t)(s0 + cOff) * F + f], v0 + v1 + v2 + v3);
        if (f == 0) atomicAdd(&cntU[s0 + cOff], 4.f);
    } else {
        atomicAdd(&poolU[(size_t)(s0 + cOff) * F + f], v0);
        atomicAdd(&poolU[(size_t)(s1 + cOff) * F + f], v1);
        atomicAdd(&poolU[(size_t)(s2 + cOff) * F + f], v2);
        atomicAdd(&poolU[(size_t)(s3 + cOff) * F + f], v3);
        if (f == 0) {
            atomicAdd(&cntU[s0 + cOff], 1.f);
            atomicAdd(&cntU[s1 + cOff], 1.f);
            atomicAdd(&cntU[s2 + cOff], 1.f);
            atomicAdd(&cntU[s3 + cOff], 1.f);
        }
    }
}

// ------- head -------
__global__ __launch_bounds__(128) void k_head(const float* __restrict__ poolU,
                                              const float* __restrict__ cntU,
                                              const float* __restrict__ denWA,
                                              const float* __restrict__ denbA,
                                              const float* __restrict__ denWB,
                                              const float* __restrict__ denbB,
                                              const float* __restrict__ ffW,
                                              const float* __restrict__ ffb,
                                              const float* __restrict__ outW,
                                              const float* __restrict__ outb,
                                              float* __restrict__ out) {
    int c = blockIdx.x;
    int h = threadIdx.x;
    __shared__ float spA[F], spB[F], sd[H], st[H];
    if (h < F) spA[h] = poolU[(size_t)c * F + h] / fmaxf(cntU[c], 1.f);
    else {
        int u = h - F;
        spB[u] = poolU[(size_t)(c + NCRYS) * F + u] / fmaxf(cntU[c + NCRYS], 1.f);
    }
    __syncthreads();
    float accA = denbA[h], accB = denbB[h];
#pragma unroll
    for (int k = 0; k < F; ++k) {
        accA = fmaf(spA[k], denWA[k * H + h], accA);
        accB = fmaf(spB[k], denWB[k * H + h], accB);
    }
    sd[h] = fabsf(softplusf(accA) - softplusf(accB));
    __syncthreads();
    float acc = ffb[h];
#pragma unroll
    for (int k = 0; k < H; ++k) acc = fmaf(sd[k], ffW[k * H + h], acc);
    st[h] = softplusf(acc) * outW[h];
    __syncthreads();
    for (int s = 64; s > 0; s >>= 1) {
        if (h < s) st[h] += st[h + s];
        __syncthreads();
    }
    if (h == 0) out[c] = st[0] + outb[0];
}

extern "C" void kernel_launch(void* const* d_in, const int* in_sizes, int n_in,
                              void* d_out, int out_size, void* d_ws, size_t ws_size,
                              hipStream_t stream) {
    const float* atomA = (const float*)d_in[0];
    const float* nbrA  = (const float*)d_in[1];
    const int*   idxA  = (const int*)d_in[2];
    const int*   segA  = (const int*)d_in[3];
    const float* embWA = (const float*)d_in[4];
    const float* embbA = (const float*)d_in[5];
    const float* convWA = (const float*)d_in[6];
    const float* convbA = (const float*)d_in[7];
    const float* bn1A  = (const float*)d_in[8];
    const float* bn2A  = (const float*)d_in[9];
    const float* denWA = (const float*)d_in[10];
    const float* denbA = (const float*)d_in[11];
    const float* atomB = (const float*)d_in[12];
    const float* nbrB  = (const float*)d_in[13];
    const int*   idxB  = (const int*)d_in[14];
    const int*   segB  = (const int*)d_in[15];
    const float* embWB = (const float*)d_in[16];
    const float* embbB = (const float*)d_in[17];
    const float* convWB = (const float*)d_in[18];
    const float* convbB = (const float*)d_in[19];
    const float* bn1B  = (const float*)d_in[20];
    const float* bn2B  = (const float*)d_in[21];
    const float* denWB = (const float*)d_in[22];
    const float* denbB = (const float*)d_in[23];
    const float* ffW   = (const float*)d_in[24];
    const float* ffb   = (const float*)d_in[25];
    const float* outW  = (const float*)d_in[26];
    const float* outb  = (const float*)d_in[27];

    unsigned* y1p = (unsigned*)d_ws;
    unsigned* y2p = y1p + (size_t)2 * NATOM * 64;
    float* poolU = (float*)(y2p + (size_t)2 * NATOM * 64);
    float* cntU  = poolU + 2 * NCRYS * F;
    unsigned* w3t  = (unsigned*)(cntU + 2 * NCRYS);
    unsigned* w12h = w3t + 24576;
    unsigned* w12l = w12h + 49152;
    unsigned* embh = w12l + 49152;
    unsigned* embl = embh + 6144;
    unsigned* nbrb = embl + 6144;
    unsigned* aP   = nbrb + (size_t)2 * NATOM * MNBR * 24;

    hipMemsetAsync(poolU, 0, (size_t)(2 * NCRYS * F + 2 * NCRYS) * sizeof(float), stream);
    k_wcvt<<<312, 256, 0, stream>>>(convWA, convWB, embWA, embWB, w3t, w12h, w12l, embh, embl);
    k_nbrcvt<<<7500, 256, 0, stream>>>(nbrA, nbrB, (uint4*)nbrb);
    k_embed<<<2 * NATOM / 32, 256, 0, stream>>>(atomA, atomB, embh, embl, embbA, embbB, aP);
    for (int l = 0; l < NCONV; ++l) {
        k_y12<<<2 * NATOM / 32, 256, 0, stream>>>(aP, w12h, w12l, l,
                                                  (unsigned short*)y1p, (unsigned short*)y2p);
        k_convfused<<<2 * NATOM / 4, 256, 0, stream>>>(
            y1p, y2p, (const unsigned short*)nbrb, idxA, idxB, w3t, l,
            convbA + l * H, convbB + l * H,
            bn1A + l * 4 * H, bn1B + l * 4 * H,
            bn2A + l * 4 * F, bn2B + l * 4 * F,
            aP);
    }
    k_pool<<<2 * NATOM * F / (256 * 4), 256, 0, stream>>>(aP, segA, segB, poolU, cntU);
    k_head<<<NCRYS, 128, 0, stream>>>(poolU, cntU, denWA, denbA, denWB, denbB,
                                      ffW, ffb, outW, outb, (float*)d_out);
}

// Round 15
// 235.975 us; speedup vs baseline: 1.0597x; 1.0081x over previous
//
#include <hip/hip_runtime.h>

// Paired CGCNN (separated) — R15.
// R15 vs R14: (1) conv launch_bounds(256,8) (was 6) — LDS 11.8KB/VGPR 36 allow
// 8 blocks/CU; (2) BN1 folded OUT of conv: wcvt pre-scales W3 columns by s1;
// y12 epilogue writes y1''=y1*s1+h1 and y2'=y2*s1. Conv z = acc + y1'' + g'
// (pure adds); sS1/sH1 LDS + preamble removed from conv.

constexpr int NATOM = 20000;
constexpr int MNBR  = 12;
constexpr int ORIG  = 92;
constexpr int NBRF  = 41;
constexpr int F     = 64;
constexpr int H     = 128;
constexpr int NCONV = 3;
constexpr int NCRYS = 400;

#define DEVFN __device__ __forceinline__

typedef __attribute__((ext_vector_type(8))) short short8;
typedef __attribute__((ext_vector_type(4))) float f32x4;

DEVFN float softplusf(float x) {
    return fmaxf(x, 0.f) + __logf(1.f + __expf(-fabsf(x)));
}
DEVFN float sigmoidf(float x) {
    return __builtin_amdgcn_rcpf(1.f + __expf(-x));
}
DEVFN unsigned short f2bf(float x) {
    union { float f; unsigned u; } v{x};
    unsigned r = v.u + 0x7FFF + ((v.u >> 16) & 1);
    return (unsigned short)(r >> 16);
}
DEVFN float bf2f(unsigned short h) {
    union { unsigned u; float f; } v;
    v.u = (unsigned)h << 16;
    return v.f;
}
DEVFN unsigned pk2(float a, float b) {
    return (unsigned)f2bf(a) | ((unsigned)f2bf(b) << 16);
}
DEVFN unsigned short f2h(float x) {
    _Float16 h = (_Float16)x;
    union { _Float16 h; unsigned short u; } v{h};
    return v.u;
}
DEVFN float h2f(unsigned short u) {
    union { unsigned short u; _Float16 h; } v{u};
    return (float)v.h;
}
DEVFN unsigned packlo(unsigned a, unsigned b) { return (a & 0xffffu) | (b << 16); }
DEVFN unsigned packhi(unsigned a, unsigned b) { return (a >> 16) | (b & 0xffff0000u); }

DEVFN float bn_scale(const float* bn, int c, int C) {
    // bn layout (4,C): g, beta, mu, var
    return bn[c] * rsqrtf(bn[3 * C + c] + 1e-5f);
}

// ------- wcvt: W3^T bf16 PRE-SCALED by s1 + W12^T hi/lo + embW^T hi/lo -------
__global__ __launch_bounds__(256) void k_wcvt(const float* __restrict__ convW_A,
                                              const float* __restrict__ convW_B,
                                              const float* __restrict__ embWA,
                                              const float* __restrict__ embWB,
                                              const float* __restrict__ bn1A,
                                              const float* __restrict__ bn1B,
                                              unsigned* __restrict__ w3t,
                                              unsigned* __restrict__ w12h,
                                              unsigned* __restrict__ w12l,
                                              unsigned* __restrict__ embh,
                                              unsigned* __restrict__ embl) {
    int e = blockIdx.x * 256 + threadIdx.x;
    if (e < 24576) {
        int mat = e >> 12;
        int rem = e & 4095;
        int col = rem >> 5, kp = rem & 31, k = kp * 2;
        int br = mat / 3, l = mat - br * 3;
        const float* src = (br ? convW_B : convW_A) + (size_t)l * (2 * F + NBRF) * H + 128 * H;
        const float* bn1 = (br ? bn1B : bn1A) + (size_t)l * 4 * H;
        float s1 = bn_scale(bn1, col, H);       // pre-scale this column
        float v0 = (k < NBRF) ? src[k * H + col] * s1 : 0.f;
        float v1 = (k + 1 < NBRF) ? src[(k + 1) * H + col] * s1 : 0.f;
        w3t[e] = pk2(v0, v1);
    } else if (e < 73728) {
        int e2 = e - 24576;
        int mat = e2 >> 13;
        int rem = e2 & 8191;
        int col = rem >> 5, kp = rem & 31, k = kp * 2;
        const float* src = (mat >= 3 ? convW_B : convW_A) + (size_t)(mat % 3) * (2 * F + NBRF) * H;
        float v0, v1;
        if (col < 128) { v0 = src[k * H + col];              v1 = src[(k + 1) * H + col]; }
        else           { v0 = src[(64 + k) * H + col - 128]; v1 = src[(64 + k + 1) * H + col - 128]; }
        unsigned short h0 = f2bf(v0), h1 = f2bf(v1);
        w12h[e2] = (unsigned)h0 | ((unsigned)h1 << 16);
        w12l[e2] = (unsigned)f2bf(v0 - bf2f(h0)) | ((unsigned)f2bf(v1 - bf2f(h1)) << 16);
    } else {
        int e3 = e - 73728;
        int br = e3 / 3072;
        int rem = e3 - br * 3072;
        int col = rem / 48, kp = rem - col * 48, k = kp * 2;
        const float* src = br ? embWB : embWA;
        float v0 = (k < ORIG) ? src[k * F + col] : 0.f;
        float v1 = (k + 1 < ORIG) ? src[(k + 1) * F + col] : 0.f;
        unsigned short h0 = f2bf(v0), h1 = f2bf(v1);
        embh[e3] = (unsigned)h0 | ((unsigned)h1 << 16);
        embl[e3] = (unsigned)f2bf(v0 - bf2f(h0)) | ((unsigned)f2bf(v1 - bf2f(h1)) << 16);
    }
}

// ------- nbrcvt v2: LDS-recoalesced; 64 rows/block -------
__global__ __launch_bounds__(256) void k_nbrcvt(const float* __restrict__ nbrA,
                                                const float* __restrict__ nbrB,
                                                uint4* __restrict__ out) {
    __shared__ __align__(16) float sIn[64 * NBRF];
    int t = threadIdx.x;
    int b = blockIdx.x;
    int br = b >= 3750;
    int lrow0 = (b - br * 3750) * 64;
    const float4* src4 = (const float4*)((br ? nbrB : nbrA) + (size_t)lrow0 * NBRF);
#pragma unroll
    for (int it = 0; it < 3; ++it) {
        int e = t + it * 256;
        if (e < 656) ((float4*)sIn)[e] = src4[e];
    }
    __syncthreads();
    int grow0 = br * (NATOM * MNBR) + lrow0;
    uint4* dst = out + (size_t)grow0 * 6;
#pragma unroll
    for (int it = 0; it < 2; ++it) {
        int c = t + it * 256;
        if (c < 384) {
            int row = c / 6, sub = c - row * 6;
            const float* s = sIn + row * NBRF;
            int k0 = sub * 8;
            float v[8];
#pragma unroll
            for (int j = 0; j < 8; ++j) v[j] = (k0 + j < NBRF) ? s[k0 + j] : 0.f;
            uint4 o;
            o.x = pk2(v[0], v[1]);
            o.y = pk2(v[2], v[3]);
            o.z = pk2(v[4], v[5]);
            o.w = pk2(v[6], v[7]);
            dst[c] = o;
        }
    }
}

// ------- embed: MFMA hi/lo; writes packed aP -------
__global__ __launch_bounds__(256) void k_embed(const float* __restrict__ atomA,
                                               const float* __restrict__ atomB,
                                               const unsigned* __restrict__ embh,
                                               const unsigned* __restrict__ embl,
                                               const float* __restrict__ embbA,
                                               const float* __restrict__ embbB,
                                               unsigned* __restrict__ aP) {
    __shared__ __align__(16) unsigned short sH[32 * 104];
    __shared__ __align__(16) unsigned short sL[32 * 104];
    int t = threadIdx.x;
    int atom0 = blockIdx.x * 32;
    int br = atom0 >= NATOM;
    const float* src = (br ? atomB : atomA) + (size_t)(atom0 - br * NATOM) * ORIG;

#pragma unroll
    for (int it = 0; it < 3; ++it) {
        int idx = t + it * 256;
        if (idx < 736) {
            int row = idx / 23, sub = idx - row * 23;
            float4 v = *(const float4*)(src + (size_t)row * ORIG + sub * 4);
            int o = row * 104 + sub * 4;
            unsigned short h0 = f2bf(v.x), h1 = f2bf(v.y), h2 = f2bf(v.z), h3 = f2bf(v.w);
            *(uint2*)(sH + o) = uint2{(unsigned)h0 | ((unsigned)h1 << 16),
                                      (unsigned)h2 | ((unsigned)h3 << 16)};
            *(uint2*)(sL + o) = uint2{(unsigned)f2bf(v.x - bf2f(h0)) | ((unsigned)f2bf(v.y - bf2f(h1)) << 16),
                                      (unsigned)f2bf(v.z - bf2f(h2)) | ((unsigned)f2bf(v.w - bf2f(h3)) << 16)};
        } else if (idx < 768) {
            int row = idx - 736;
            *(uint2*)(sH + row * 104 + 92) = uint2{0, 0};
            *(uint2*)(sL + row * 104 + 92) = uint2{0, 0};
        }
    }

    int w = t >> 6, lane = t & 63;
    int lr = lane & 15, lq = lane >> 4;
    int col = w * 16 + lr;

    const unsigned short* bh_base = (const unsigned short*)embh + (size_t)br * 6144 + (size_t)col * 96;
    const unsigned short* bl_base = (const unsigned short*)embl + (size_t)br * 6144 + (size_t)col * 96;
    short8 bh[3], bl[3];
#pragma unroll
    for (int ks = 0; ks < 3; ++ks) {
        bh[ks] = *(const short8*)(bh_base + ks * 32 + lq * 8);
        bl[ks] = *(const short8*)(bl_base + ks * 32 + lq * 8);
    }
    __syncthreads();

    f32x4 acc[2];
    acc[0] = f32x4{0.f, 0.f, 0.f, 0.f};
    acc[1] = f32x4{0.f, 0.f, 0.f, 0.f};
#pragma unroll
    for (int ks = 0; ks < 3; ++ks) {
        int ko = ks * 32 + lq * 8;
        short8 ah[2], al[2];
#pragma unroll
        for (int r = 0; r < 2; ++r) {
            ah[r] = *(const short8*)(sH + (r * 16 + lr) * 104 + ko);
            al[r] = *(const short8*)(sL + (r * 16 + lr) * 104 + ko);
        }
#pragma unroll
        for (int r = 0; r < 2; ++r) {
            acc[r] = __builtin_amdgcn_mfma_f32_16x16x32_bf16(ah[r], bh[ks], acc[r], 0, 0, 0);
            acc[r] = __builtin_amdgcn_mfma_f32_16x16x32_bf16(ah[r], bl[ks], acc[r], 0, 0, 0);
            acc[r] = __builtin_amdgcn_mfma_f32_16x16x32_bf16(al[r], bh[ks], acc[r], 0, 0, 0);
        }
    }

    float bias = (br ? embbB : embbA)[col];
#pragma unroll
    for (int r = 0; r < 2; ++r)
#pragma unroll
        for (int q = 0; q < 4; ++q) {
            int atom = atom0 + r * 16 + lq * 4 + q;
            float val = acc[r][q] + bias;
            unsigned short h = f2bf(val);
            aP[(unsigned)(atom * F + col)] = (unsigned)h | ((unsigned)f2bf(val - bf2f(h)) << 16);
        }
}

// ------- y12: outputs y1'' = y1*s1+h1 (filt/core) and y2' = y2*s1 -------
__global__ __launch_bounds__(256, 2) void k_y12(const unsigned* __restrict__ aP,
                                                const unsigned* __restrict__ w12h_base,
                                                const unsigned* __restrict__ w12l_base,
                                                int layer,
                                                const float* __restrict__ bn1A,
                                                const float* __restrict__ bn1B,
                                                const float* __restrict__ convbA,
                                                const float* __restrict__ convbB,
                                                unsigned short* __restrict__ y1u,
                                                unsigned short* __restrict__ y2u) {
    __shared__ __align__(16) unsigned short sH[32 * 72];
    __shared__ __align__(16) unsigned short sL[32 * 72];
    int t = threadIdx.x;
    int atom0 = blockIdx.x * 32;
    int br = atom0 >= NATOM;
    int mat = br * 3 + layer;
    const unsigned short* w12h = (const unsigned short*)(w12h_base + (size_t)mat * 8192);
    const unsigned short* w12l = (const unsigned short*)(w12l_base + (size_t)mat * 8192);
    const float* bn1 = (br ? bn1B : bn1A) + (size_t)layer * 4 * H;
    const float* cvb = (br ? convbB : convbA) + (size_t)layer * H;
#pragma unroll
    for (int it = 0; it < 2; ++it) {
        int c = t + it * 256;
        int row = c >> 4, sub = c & 15;
        uint4 u = *(const uint4*)(aP + (unsigned)((atom0 + row) * 64 + sub * 4));
        *(uint2*)(sH + row * 72 + sub * 4) = uint2{packlo(u.x, u.y), packlo(u.z, u.w)};
        *(uint2*)(sL + row * 72 + sub * 4) = uint2{packhi(u.x, u.y), packhi(u.z, u.w)};
    }
    int w = t >> 6, lane = t & 63;
    int lr = lane & 15, lq = lane >> 4;

    short8 bh[2][4], bl[2][4];
#pragma unroll
    for (int kstep = 0; kstep < 2; ++kstep)
#pragma unroll
        for (int n = 0; n < 4; ++n) {
            int col = w * 64 + n * 16 + lr;
            size_t off = (size_t)col * 64 + kstep * 32 + lq * 8;
            bh[kstep][n] = *(const short8*)(w12h + off);
            bl[kstep][n] = *(const short8*)(w12l + off);
        }
    __syncthreads();

    f32x4 acc[4][2];
#pragma unroll
    for (int n = 0; n < 4; ++n)
#pragma unroll
        for (int r = 0; r < 2; ++r) acc[n][r] = f32x4{0.f, 0.f, 0.f, 0.f};

#pragma unroll
    for (int kstep = 0; kstep < 2; ++kstep) {
        int ks = kstep * 32 + lq * 8;
        short8 ah[2], al[2];
#pragma unroll
        for (int r = 0; r < 2; ++r) {
            ah[r] = *(const short8*)(sH + (r * 16 + lr) * 72 + ks);
            al[r] = *(const short8*)(sL + (r * 16 + lr) * 72 + ks);
        }
#pragma unroll
        for (int n = 0; n < 4; ++n)
#pragma unroll
            for (int r = 0; r < 2; ++r) {
                acc[n][r] = __builtin_amdgcn_mfma_f32_16x16x32_bf16(ah[r], bh[kstep][n], acc[n][r], 0, 0, 0);
                acc[n][r] = __builtin_amdgcn_mfma_f32_16x16x32_bf16(ah[r], bl[kstep][n], acc[n][r], 0, 0, 0);
                acc[n][r] = __builtin_amdgcn_mfma_f32_16x16x32_bf16(al[r], bh[kstep][n], acc[n][r], 0, 0, 0);
            }
    }

#pragma unroll
    for (int n = 0; n < 4; ++n) {
        int c = w * 64 + n * 16 + lr;          // 0..255
        int cc = c & 127;                      // z-column
        float s1 = bn_scale(bn1, cc, H);
        int p = cc >> 6, cb = cc & 63;
        unsigned short* dst;
        float scale, shift;
        if (c < 128) {                         // y1 path: y1'' = y1*s1 + h1
            float h1 = bn1[H + cc] - bn1[2 * H + cc] * s1 + cvb[cc] * s1;
            dst = y1u + cb * 2 + p;
            scale = s1; shift = h1;
        } else {                               // y2 path: y2' = y2*s1
            dst = y2u + cb * 2 + p;
            scale = s1; shift = 0.f;
        }
#pragma unroll
        for (int r = 0; r < 2; ++r)
#pragma unroll
            for (int q = 0; q < 4; ++q) {
                int atom = atom0 + r * 16 + lq * 4 + q;
                dst[(unsigned)(atom * 128)] = f2h(acc[n][r][q] * scale + shift);
            }
    }
}

// ------- conv: pre-scaled W3, pure-add epilogue, launch_bounds(256,8) -------
__global__ __launch_bounds__(256, 8) void k_convfused(
        const unsigned* __restrict__ y1p,
        const unsigned* __restrict__ y2p,
        const unsigned short* __restrict__ nbrb,
        const int* __restrict__ idxA, const int* __restrict__ idxB,
        const unsigned* __restrict__ w3t, int layer,
        const float* __restrict__ bn2A,  const float* __restrict__ bn2B,
        unsigned* __restrict__ aP) {
    __shared__ __align__(16) unsigned char sAbuf[48 * 144];
    __shared__ float sS2[64], sH2[64];
    __shared__ float sp[12 * 65 + 3];
    __shared__ __align__(16) int sJ[48];

    int t = threadIdx.x;
    int atom0 = blockIdx.x * 4;
    int br = atom0 >= NATOM;
    int brOff = br * NATOM;
    unsigned R0 = (unsigned)atom0 * MNBR;
    const float* bn2 = br ? bn2B : bn2A;
    const unsigned short* w3l = (const unsigned short*)(w3t + (size_t)(br * 3 + layer) * 4096);
    const unsigned* y2b = y2p + (size_t)brOff * 64;
    const unsigned* y1b = y1p + (size_t)atom0 * 64;
    unsigned* aPb = aP + (size_t)atom0 * 64;

#pragma unroll
    for (int jj = 0; jj < 2; ++jj) {
        int c = t + jj * 256;
        if (c < 384) {
            int row = c >> 3, sub = c & 7;
            short8 v = short8{0, 0, 0, 0, 0, 0, 0, 0};
            if (sub < 6) v = *(const short8*)(nbrb + ((R0 + row) * 48u + sub * 8u));
            *(short8*)(sAbuf + row * 144 + sub * 16) = v;
        }
    }
    if (t < 64) {
        float g = bn2[t], be = bn2[64 + t], mu = bn2[128 + t], va = bn2[192 + t];
        float s = g * rsqrtf(va + 1e-5f);
        sS2[t] = s;
        sH2[t] = be - mu * s;
    } else if (t >= 64 && t < 112) {
        sJ[t - 64] = ((br ? idxB : idxA) + (size_t)(atom0 - brOff) * MNBR)[t - 64];
    }

    int w = t >> 6, lane = t & 63;
    int lr = lane & 15, lq = lane >> 4;
    int f = w * 16 + lr;

    short8 bfr[2][2];
#pragma unroll
    for (int kstep = 0; kstep < 2; ++kstep) {
        int ks = kstep * 32 + lq * 8;
        bfr[kstep][0] = *(const short8*)(w3l + (unsigned)(f * 64 + ks));
        bfr[kstep][1] = *(const short8*)(w3l + (unsigned)((64 + f) * 64 + ks));
    }
    __syncthreads();

    f32x4 acc[2][3];
#pragma unroll
    for (int n = 0; n < 2; ++n)
#pragma unroll
        for (int r = 0; r < 3; ++r) acc[n][r] = f32x4{0.f, 0.f, 0.f, 0.f};

#pragma unroll
    for (int kstep = 0; kstep < 2; ++kstep) {
        int ks = kstep * 32 + lq * 8;
        short8 af[3];
#pragma unroll
        for (int r = 0; r < 3; ++r) {
            int row = r * 16 + lr;
            af[r] = *(const short8*)(sAbuf + row * 144 + ks * 2);
        }
#pragma unroll
        for (int n = 0; n < 2; ++n)
#pragma unroll
            for (int r = 0; r < 3; ++r)
                acc[n][r] = __builtin_amdgcn_mfma_f32_16x16x32_bf16(af[r], bfr[kstep][n], acc[n][r], 0, 0, 0);
    }

#pragma unroll
    for (int r = 0; r < 3; ++r) {
        int rowbase = 16 * r + 4 * lq;
        int4 jq = *(const int4*)(sJ + rowbase);
        int atom = (4 * r + lq) / 3;
        unsigned y1v = y1b[(unsigned)(atom * 64 + f)];
        float y1f = h2f((unsigned short)(y1v & 0xffff));
        float y1c = h2f((unsigned short)(y1v >> 16));
        unsigned g0 = y2b[(unsigned)jq.x * 64u + (unsigned)f];
        unsigned g1 = y2b[(unsigned)jq.y * 64u + (unsigned)f];
        unsigned g2 = y2b[(unsigned)jq.z * 64u + (unsigned)f];
        unsigned g3 = y2b[(unsigned)jq.w * 64u + (unsigned)f];
        unsigned gv[4] = {g0, g1, g2, g3};
        float partial = 0.f;
#pragma unroll
        for (int q = 0; q < 4; ++q) {
            float zf = acc[0][r][q] + y1f + h2f((unsigned short)(gv[q] & 0xffff));
            float zc = acc[1][r][q] + y1c + h2f((unsigned short)(gv[q] >> 16));
            partial += sigmoidf(zf) * softplusf(zc);
        }
        sp[(4 * r + lq) * 65 + f] = partial;
    }
    __syncthreads();

    int al = t >> 6, f2 = t & 63;
    float sacc = sp[(3 * al + 0) * 65 + f2] + sp[(3 * al + 1) * 65 + f2] + sp[(3 * al + 2) * 65 + f2];
    unsigned o = (unsigned)(al * 64 + f2);
    unsigned au = aPb[o];
    float av = bf2f((unsigned short)(au & 0xffff)) + bf2f((unsigned short)(au >> 16));
    float res = softplusf(av + sacc * sS2[f2] + sH2[f2]);
    unsigned short hh = f2bf(res);
    aPb[o] = (unsigned)hh | ((unsigned)f2bf(res - bf2f(hh)) << 16);
}

// ------- pool: packed aP, 4-atom groups -------
__global__ __launch_bounds__(256) void k_pool(const unsigned* __restrict__ aP,
                                              const int* __restrict__ segA,
                                              const int* __restrict__ segB,
                                              float* __restrict__ poolU,
                                              float* __restrict__ cntU) {
    int t = threadIdx.x;
    int f = t & 63, g = t >> 6;
    int n0 = blockIdx.x * 16 + g * 4;
    int br = n0 >= NATOM;
    const int* seg = br ? segB : segA;
    int nl = n0 - br * NATOM;
    int s0 = seg[nl], s1 = seg[nl + 1], s2 = seg[nl + 2], s3 = seg[nl + 3];
    unsigned u0 = aP[(unsigned)((n0 + 0) * F + f)];
    unsigned u1 = aP[(unsigned)((n0 + 1) * F + f)];
    unsigned u2 = aP[(unsigned)((n0 + 2) * F + f)];
    unsigned u3 = aP[(unsigned)((n0 + 3) * F + f)];
    float v0 = bf2f((unsigned short)(u0 & 0xffff)) + bf2f((unsigned short)(u0 >> 16));
    float v1 = bf2f((unsigned short)(u1 & 0xffff)) + bf2f((unsigned short)(u1 >> 16));
    float v2 = bf2f((unsigned short)(u2 & 0xffff)) + bf2f((unsigned short)(u2 >> 16));
    float v3 = bf2f((unsigned short)(u3 & 0xffff)) + bf2f((unsigned short)(u3 >> 16));
    int cOff = br * NCRYS;
    if (s0 == s3) {
        atomicAdd(&poolU[(size_t)(s0 + cOff) * F + f], v0 + v1 + v2 + v3);
        if (f == 0) atomicAdd(&cntU[s0 + cOff], 4.f);
    } else {
        atomicAdd(&poolU[(size_t)(s0 + cOff) * F + f], v0);
        atomicAdd(&poolU[(size_t)(s1 + cOff) * F + f], v1);
        atomicAdd(&poolU[(size_t)(s2 + cOff) * F + f], v2);
        atomicAdd(&poolU[(size_t)(s3 + cOff) * F + f], v3);
        if (f == 0) {
            atomicAdd(&cntU[s0 + cOff], 1.f);
            atomicAdd(&cntU[s1 + cOff], 1.f);
            atomicAdd(&cntU[s2 + cOff], 1.f);
            atomicAdd(&cntU[s3 + cOff], 1.f);
        }
    }
}

// ------- head -------
__global__ __launch_bounds__(128) void k_head(const float* __restrict__ poolU,
                                              const float* __restrict__ cntU,
                                              const float* __restrict__ denWA,
                                              const float* __restrict__ denbA,
                                              const float* __restrict__ denWB,
                                              const float* __restrict__ denbB,
                                              const float* __restrict__ ffW,
                                              const float* __restrict__ ffb,
                                              const float* __restrict__ outW,
                                              const float* __restrict__ outb,
                                              float* __restrict__ out) {
    int c = blockIdx.x;
    int h = threadIdx.x;
    __shared__ float spA[F], spB[F], sd[H], st[H];
    if (h < F) spA[h] = poolU[(size_t)c * F + h] / fmaxf(cntU[c], 1.f);
    else {
        int u = h - F;
        spB[u] = poolU[(size_t)(c + NCRYS) * F + u] / fmaxf(cntU[c + NCRYS], 1.f);
    }
    __syncthreads();
    float accA = denbA[h], accB = denbB[h];
#pragma unroll
    for (int k = 0; k < F; ++k) {
        accA = fmaf(spA[k], denWA[k * H + h], accA);
        accB = fmaf(spB[k], denWB[k * H + h], accB);
    }
    sd[h] = fabsf(softplusf(accA) - softplusf(accB));
    __syncthreads();
    float acc = ffb[h];
#pragma unroll
    for (int k = 0; k < H; ++k) acc = fmaf(sd[k], ffW[k * H + h], acc);
    st[h] = softplusf(acc) * outW[h];
    __syncthreads();
    for (int s = 64; s > 0; s >>= 1) {
        if (h < s) st[h] += st[h + s];
        __syncthreads();
    }
    if (h == 0) out[c] = st[0] + outb[0];
}

extern "C" void kernel_launch(void* const* d_in, const int* in_sizes, int n_in,
                              void* d_out, int out_size, void* d_ws, size_t ws_size,
                              hipStream_t stream) {
    const float* atomA = (const float*)d_in[0];
    const float* nbrA  = (const float*)d_in[1];
    const int*   idxA  = (const int*)d_in[2];
    const int*   segA  = (const int*)d_in[3];
    const float* embWA = (const float*)d_in[4];
    const float* embbA = (const float*)d_in[5];
    const float* convWA = (const float*)d_in[6];
    const float* convbA = (const float*)d_in[7];
    const float* bn1A  = (const float*)d_in[8];
    const float* bn2A  = (const float*)d_in[9];
    const float* denWA = (const float*)d_in[10];
    const float* denbA = (const float*)d_in[11];
    const float* atomB = (const float*)d_in[12];
    const float* nbrB  = (const float*)d_in[13];
    const int*   idxB  = (const int*)d_in[14];
    const int*   segB  = (const int*)d_in[15];
    const float* embWB = (const float*)d_in[16];
    const float* embbB = (const float*)d_in[17];
    const float* convWB = (const float*)d_in[18];
    const float* convbB = (const float*)d_in[19];
    const float* bn1B  = (const float*)d_in[20];
    const float* bn2B  = (const float*)d_in[21];
    const float* denWB = (const float*)d_in[22];
    const float* denbB = (const float*)d_in[23];
    const float* ffW   = (const float*)d_in[24];
    const float* ffb   = (const float*)d_in[25];
    const float* outW  = (const float*)d_in[26];
    const float* outb  = (const float*)d_in[27];

    unsigned* y1p = (unsigned*)d_ws;
    unsigned* y2p = y1p + (size_t)2 * NATOM * 64;
    float* poolU = (float*)(y2p + (size_t)2 * NATOM * 64);
    float* cntU  = poolU + 2 * NCRYS * F;
    unsigned* w3t  = (unsigned*)(cntU + 2 * NCRYS);
    unsigned* w12h = w3t + 24576;
    unsigned* w12l = w12h + 49152;
    unsigned* embh = w12l + 49152;
    unsigned* embl = embh + 6144;
    unsigned* nbrb = embl + 6144;
    unsigned* aP   = nbrb + (size_t)2 * NATOM * MNBR * 24;

    hipMemsetAsync(poolU, 0, (size_t)(2 * NCRYS * F + 2 * NCRYS) * sizeof(float), stream);
    k_wcvt<<<312, 256, 0, stream>>>(convWA, convWB, embWA, embWB, bn1A, bn1B,
                                    w3t, w12h, w12l, embh, embl);
    k_nbrcvt<<<7500, 256, 0, stream>>>(nbrA, nbrB, (uint4*)nbrb);
    k_embed<<<2 * NATOM / 32, 256, 0, stream>>>(atomA, atomB, embh, embl, embbA, embbB, aP);
    for (int l = 0; l < NCONV; ++l) {
        k_y12<<<2 * NATOM / 32, 256, 0, stream>>>(aP, w12h, w12l, l,
                                                  bn1A, bn1B, convbA, convbB,
                                                  (unsigned short*)y1p, (unsigned short*)y2p);
        k_convfused<<<2 * NATOM / 4, 256, 0, stream>>>(
            y1p, y2p, (const unsigned short*)nbrb, idxA, idxB, w3t, l,
            bn2A + l * 4 * F, bn2B + l * 4 * F,
            aP);
    }
    k_pool<<<2 * NATOM * F / (256 * 4), 256, 0, stream>>>(aP, segA, segB, poolU, cntU);
    k_head<<<NCRYS, 128, 0, stream>>>(poolU, cntU, denWA, denbA, denWB, denbB,
                                      ffW, ffb, outW, outb, (float*)d_out);
}